// Round 1
// 165.954 us; speedup vs baseline: 1.0003x; 1.0003x over previous
//
#include <hip/hip_runtime.h>

typedef unsigned short u16;
typedef unsigned int u32;
typedef unsigned char u8;

#define HW 32768
#define NPX 65536
#define GEO_SIZE 8388608   /* 2*128*32768 elements */
#define EPS 1e-5f

// ---- workspace layout ----
// f32-index offsets into ws (float*):
#define OFF_PWP   0        /* 128 float4 = 512 f32 */
#define OFF_EWP   512      /* 128 float4 */
#define OFF_SHE   1024     /* 3 f32 */
#define OFF_FLG   1028     /* [0]=is_bf16, [1]=mask_encoding */
#define OFF_SHF   1088     /* 128 f32 bn_f shift */
// byte offsets:
#define W2T_OFF   8192     /* bf16 [128 o][128 c] = 32768 B */
#define EAP_OFF   131072   /* f32 [8 grp][3 d][NPX] = 6291456 B */
#define T_OFF     8388608  /* bf16 t[o][px] = 128*65536*2 = 16777216 B */

typedef __bf16 bf16x8 __attribute__((ext_vector_type(8)));
typedef float f32x4 __attribute__((ext_vector_type(4)));
typedef float f32x2 __attribute__((ext_vector_type(2)));

__device__ __forceinline__ float bf2f(u16 u){ return __uint_as_float(((u32)u) << 16); }
__device__ __forceinline__ u16 f2bf(float f){
  u32 x = __float_as_uint(f);
  return (u16)((x + 0x7fffu + ((x >> 16) & 1u)) >> 16);
}
__device__ __forceinline__ float bflo(u32 w){ return __uint_as_float(w << 16); }
__device__ __forceinline__ float bfhi(u32 w){ return __uint_as_float(w & 0xffff0000u); }

__device__ __forceinline__ f32x2 pk_fma(f32x2 a, f32x2 b, f32x2 c){
  return __builtin_elementwise_fma(a, b, c);
}
__device__ __forceinline__ f32x2 pk_max(f32x2 a, f32x2 b){
  return __builtin_elementwise_max(a, b);
}

__device__ __forceinline__ float ldp(const void* p, int i, bool isbf){
  return isbf ? bf2f(((const u16*)p)[i]) : ((const float*)p)[i];
}

__device__ __forceinline__ bool sniff_bf16(const void* fv){
  const u16* w = (const u16*)fv;
  int hits = 0;
  for (int i = 0; i < 32; i++) {
    float v = bf2f(w[i]);
    hits += (v >= 0.45f && v <= 1.55f) ? 1 : 0;
  }
  return hits >= 26;
}

__device__ __forceinline__ int sniff_mask(const void* mask){
  const u8* mb = (const u8*)mask;
  int c01 = 0, ones = 0;
  for (int i = 0; i < 64; i++) { u8 v = mb[i]; c01 += (v <= 1); ones += (v == 1); }
  if (c01 == 64) return (ones >= 24) ? 0 : 1;
  const u16* mw = (const u16*)mask;
  int c3f = 0;
  for (int i = 0; i < 32; i++) c3f += (mw[i] == 0x3F80);
  return (c3f >= 22) ? 2 : 3;
}

__device__ __forceinline__ float mask_at(const void* m, int gi, int enc){
  if (enc == 0) return ((const u8*)m)[gi]  ? 1.f : 0.f;
  if (enc == 1) return ((const int*)m)[gi] ? 1.f : 0.f;
  if (enc == 2) return ((const u16*)m)[gi] ? 1.f : 0.f;
  return (((const float*)m)[gi] != 0.f) ? 1.f : 0.f;
}

// prep: blocks 0..31 fold fw -> w2t (1 u32 per thread); block 32 does tables.
__global__ __launch_bounds__(256) void prep_kernel(
    const void* __restrict__ pw, const void* __restrict__ pg,
    const void* __restrict__ pb, const void* __restrict__ pm,
    const void* __restrict__ pv,
    const void* __restrict__ fw, const void* __restrict__ fg,
    const void* __restrict__ fb, const void* __restrict__ fm,
    const void* __restrict__ fv,
    const void* __restrict__ ew, const void* __restrict__ eg,
    const void* __restrict__ eb, const void* __restrict__ em,
    const void* __restrict__ ev,
    const void* __restrict__ mask,
    float* __restrict__ ws){
  int blk = blockIdx.x, tid = threadIdx.x;
  bool isbf = sniff_bf16(fv);
  if (blk < 32) {
    int p = blk * 256 + tid;          // u32 index into w2t, 8192 total
    int o = p >> 6;                   // 64 u32 (=128 bf16) per o-row
    float sf = ldp(fg, o, isbf) * __frsqrt_rn(ldp(fv, o, isbf) + EPS);
    u32 outv;
    if (isbf) {
      u32 in = ((const u32*)fw)[p];
      outv = (u32)f2bf(sf * bf2f((u16)(in & 0xffff))) |
             ((u32)f2bf(sf * bf2f((u16)(in >> 16))) << 16);
    } else {
      const float* fwp = (const float*)fw;
      outv = (u32)f2bf(sf * fwp[2 * p]) | ((u32)f2bf(sf * fwp[2 * p + 1]) << 16);
    }
    ((u32*)((char*)ws + W2T_OFF))[p] = outv;
    return;
  }
  int o = tid;
  if (o == 0) {
    ws[OFF_FLG]     = isbf ? 1.f : 0.f;
    ws[OFF_FLG + 1] = (float)sniff_mask(mask);
  }
  if (o < 128) {
    float sf = ldp(fg, o, isbf) * __frsqrt_rn(ldp(fv, o, isbf) + EPS);
    ws[OFF_SHF + o] = ldp(fb, o, isbf) - ldp(fm, o, isbf) * sf;
    float sp = ldp(pg, o, isbf) * __frsqrt_rn(ldp(pv, o, isbf) + EPS);
    float4* pwp = (float4*)(ws + OFF_PWP);
    pwp[o] = make_float4(sp * ldp(pw, o * 3 + 0, isbf),
                         sp * ldp(pw, o * 3 + 1, isbf),
                         sp * ldp(pw, o * 3 + 2, isbf),
                         ldp(pb, o, isbf) - ldp(pm, o, isbf) * sp);
    float se0 = ldp(eg, 0, isbf) * __frsqrt_rn(ldp(ev, 0, isbf) + EPS);
    float se1 = ldp(eg, 1, isbf) * __frsqrt_rn(ldp(ev, 1, isbf) + EPS);
    float se2 = ldp(eg, 2, isbf) * __frsqrt_rn(ldp(ev, 2, isbf) + EPS);
    float4* ewp = (float4*)(ws + OFF_EWP);
    ewp[o] = make_float4(se0 * ldp(ew, 0 * 128 + o, isbf),
                         se1 * ldp(ew, 1 * 128 + o, isbf),
                         se2 * ldp(ew, 2 * 128 + o, isbf), 0.f);
    if (o < 3) {
      float se = ldp(eg, o, isbf) * __frsqrt_rn(ldp(ev, o, isbf) + EPS);
      ws[OFF_SHE + o] = ldp(eb, o, isbf) - ldp(em, o, isbf) * se;
    }
  }
}

// Stage 1 v2: 64-px tiles, coalesced global loads (pixels on lanes),
// XOR-swizzled linear LDS [64px][128ch] bf16 (16B-granule ^= px&15):
// both ds_write_b128 staging and ds_read_b128 fragment reads are
// conflict-free (<=2 accesses/bank per 16-lane phase).
// Grid: 1024 blocks x 256 threads.
__global__ __launch_bounds__(256) void stage1_kernel(const void* __restrict__ feat,
                                                     const float* __restrict__ ws,
                                                     u16* __restrict__ t){
  __shared__ u16 lds[128 * 72];   // 18432 B; phase A uses first 16384 B
  int tid = threadIdx.x;
  bool isbf = ws[OFF_FLG] > 0.5f;
  int pxg = blockIdx.x * 64;
  int b = pxg >> 15, hw0 = pxg & 32767;

  // ---- staging: lane l = pixel, cg selects 32-channel slab ----
  {
    int l = tid & 63, cg = tid >> 6;
    int ch0 = cg * 32;
    int base = (b * 128 + ch0) * HW + hw0 + l;
    char* rowp = (char*)lds + l * 256;
    int xs = l & 15;
    if (isbf) {
      const u16* fp = (const u16*)feat;
      u16 v[32];
#pragma unroll
      for (int i = 0; i < 32; i++) v[i] = fp[base + i * HW];
#pragma unroll
      for (int g = 0; g < 4; g++) {
        uint4 pk;
        pk.x = (u32)v[g*8+0] | ((u32)v[g*8+1] << 16);
        pk.y = (u32)v[g*8+2] | ((u32)v[g*8+3] << 16);
        pk.z = (u32)v[g*8+4] | ((u32)v[g*8+5] << 16);
        pk.w = (u32)v[g*8+6] | ((u32)v[g*8+7] << 16);
        *(uint4*)(rowp + ((((cg << 2) | g) ^ xs) << 4)) = pk;
      }
    } else {
      const float* fp = (const float*)feat;
      float v[32];
#pragma unroll
      for (int i = 0; i < 32; i++) v[i] = fp[base + i * HW];
#pragma unroll
      for (int g = 0; g < 4; g++) {
        uint4 pk;
        pk.x = (u32)f2bf(v[g*8+0]) | ((u32)f2bf(v[g*8+1]) << 16);
        pk.y = (u32)f2bf(v[g*8+2]) | ((u32)f2bf(v[g*8+3]) << 16);
        pk.z = (u32)f2bf(v[g*8+4]) | ((u32)f2bf(v[g*8+5]) << 16);
        pk.w = (u32)f2bf(v[g*8+6]) | ((u32)f2bf(v[g*8+7]) << 16);
        *(uint4*)(rowp + ((((cg << 2) | g) ^ xs) << 4)) = pk;
      }
    }
  }
  __syncthreads();

  // ---- MFMA: wave wv owns 16-px strip; 8 ot x 4 ks = 32 MFMA ----
  int wv = tid >> 6, lane = tid & 63;
  int ln = lane & 15, quad = lane >> 4;
  const uint4* W = (const uint4*)((const char*)ws + W2T_OFF);
  f32x4 acc[8];
#pragma unroll
  for (int ot = 0; ot < 8; ot++) acc[ot] = (f32x4){0.f, 0.f, 0.f, 0.f};

  const char* rbase = (const char*)lds + (wv * 16 + ln) * 256;
#pragma unroll
  for (int ks = 0; ks < 4; ks++) {
    bf16x8 bb = __builtin_bit_cast(bf16x8,
        *(const uint4*)(rbase + ((((ks << 2) | quad) ^ ln) << 4)));
    bf16x8 a[8];
#pragma unroll
    for (int ot = 0; ot < 8; ot++)
      a[ot] = __builtin_bit_cast(bf16x8, W[(ot * 16 + ln) * 16 + ks * 4 + quad]);
#pragma unroll
    for (int ot = 0; ot < 8; ot++)
      acc[ot] = __builtin_amdgcn_mfma_f32_16x16x32_bf16(a[ot], bb, acc[ot], 0, 0, 0);
  }
  __syncthreads();

  // ---- epilogue: bn shift + relu, transpose to [128 o][64 px] in LDS ----
  const float* shf = ws + OFF_SHF;
#pragma unroll
  for (int ot = 0; ot < 8; ot++) {
#pragma unroll
    for (int r = 0; r < 4; r++) {
      int o = ot * 16 + quad * 4 + r;
      float v = fmaxf(acc[ot][r] + shf[o], 0.f);
      lds[o * 72 + wv * 16 + ln] = f2bf(v);
    }
  }
  __syncthreads();
  {
    int o = tid >> 1, half = tid & 1;
    const u16* src = lds + o * 72 + half * 32;
    uint4* dst = (uint4*)(t + o * NPX + pxg + half * 32);
#pragma unroll
    for (int k = 0; k < 4; k++) dst[k] = *(const uint4*)(src + k * 8);
  }
}

// Stage 2: 2 px/thread packed f32x2, 16-channel group per block.
// Grid: 128 px-blocks x 8 groups = 1024 blocks (4 blocks/CU).
__global__ __launch_bounds__(256) void stage2_kernel(const void* __restrict__ cart,
                                                     const float* __restrict__ ws,
                                                     const void* __restrict__ rawmask,
                                                     const u16* __restrict__ t,
                                                     float* __restrict__ eap,
                                                     void* __restrict__ out){
  int tid = threadIdx.x;
  int pxb = blockIdx.x & 127, grp = blockIdx.x >> 7;
  int px0 = pxb * 512 + tid * 2;            // even
  int b = px0 >> 15, hw = px0 & 32767;
  int h = hw >> 9, w = hw & 511;            // w even
  bool isbf = ws[OFF_FLG] > 0.5f;
  int enc = (int)ws[OFF_FLG + 1];

  f32x2 rel2[9][3];
  f32x2 mv2[9];
  {
    float cr[12][3];
    float mm[12];
#pragma unroll
    for (int r = 0; r < 3; r++) {
#pragma unroll
      for (int c = 0; c < 4; c++) {
        int idx = r * 4 + c;
        int h2 = h + r - 1, w2 = w + c - 1;
        bool ok = ((unsigned)h2 < 64u) && ((unsigned)w2 < 512u);
        int hw2 = ok ? ((h2 << 9) | w2) : hw;
        int gi = b * HW + hw2;
        mm[idx] = ok ? mask_at(rawmask, gi, enc) : 0.f;
#pragma unroll
        for (int d = 0; d < 3; d++)
          cr[idx][d] = isbf ? bf2f(((const u16*)cart)[(b * 3 + d) * HW + hw2])
                            : ((const float*)cart)[(b * 3 + d) * HW + hw2];
      }
    }
#pragma unroll
    for (int r = 0; r < 3; r++)
#pragma unroll
      for (int cc = 0; cc < 3; cc++) {
        int n = r * 3 + cc;
        mv2[n] = (f32x2){mm[r * 4 + cc], mm[r * 4 + cc + 1]};
#pragma unroll
        for (int d = 0; d < 3; d++)
          rel2[n][d] = (f32x2){cr[r * 4 + cc][d] - cr[5][d],
                               cr[r * 4 + cc + 1][d] - cr[6][d]};
      }
  }

  const float4* pwp = (const float4*)(ws + OFF_PWP);
  const float4* ewp = (const float4*)(ws + OFF_EWP);
  f32x2 eA = {0.f, 0.f}, eB = {0.f, 0.f}, eC = {0.f, 0.f};
  u16* o16 = (u16*)out;
  float* of = (float*)out;
  const f32x2 zero2 = {0.f, 0.f};

#pragma unroll 4
  for (int j = 0; j < 16; j++) {
    int o = grp * 16 + j;
    const u16* tb = t + o * NPX + b * HW;
    u32 tw[3][3];
#pragma unroll
    for (int r = 0; r < 3; r++) {
      const u32* rp = (const u32*)(tb + (h + r - 1) * 512 + (w - 2));  // stays inside d_ws
      tw[r][0] = rp[0]; tw[r][1] = rp[1]; tw[r][2] = rp[2];
    }
    float4 P = pwp[o];
    f32x2 Px = {P.x, P.x}, Py = {P.y, P.y}, Pz = {P.z, P.z}, Pw = {P.w, P.w};
    f32x2 g = {0.f, 0.f};
#pragma unroll
    for (int r = 0; r < 3; r++) {
      float tm1 = bfhi(tw[r][0]);   // col w-1
      float t0  = bflo(tw[r][1]);   // col w
      float tp1 = bfhi(tw[r][1]);   // col w+1
      float tp2 = bflo(tw[r][2]);   // col w+2
      f32x2 tv[3] = {{tm1, t0}, {t0, tp1}, {tp1, tp2}};
#pragma unroll
      for (int cc = 0; cc < 3; cc++) {
        int n = r * 3 + cc;
        f32x2 pos = pk_max(pk_fma(Px, rel2[n][0],
                           pk_fma(Py, rel2[n][1],
                           pk_fma(Pz, rel2[n][2], Pw))), zero2);
        g = pk_max(g, (tv[cc] + pos) * mv2[n]);
      }
    }
    int gi = (b * 128 + o) * HW + hw;
    if (isbf) *(u32*)(o16 + gi) = (u32)f2bf(g.x) | ((u32)f2bf(g.y) << 16);
    else { of[gi] = g.x; of[gi + 1] = g.y; }
    float4 E = ewp[o];
    eA = pk_fma((f32x2){E.x, E.x}, g, eA);
    eB = pk_fma((f32x2){E.y, E.y}, g, eB);
    eC = pk_fma((f32x2){E.z, E.z}, g, eC);
  }
  *(f32x2*)(eap + (grp * 3 + 0) * NPX + px0) = eA;
  *(f32x2*)(eap + (grp * 3 + 1) * NPX + px0) = eB;
  *(f32x2*)(eap + (grp * 3 + 2) * NPX + px0) = eC;
}

// Final: sum 8 group partials, cart_out. 2 px/thread, grid 128.
__global__ __launch_bounds__(256) void final_kernel(const void* __restrict__ cart,
                                                    const float* __restrict__ ws,
                                                    const void* __restrict__ rawmask,
                                                    const float* __restrict__ eap,
                                                    void* __restrict__ out){
  int px0 = (blockIdx.x * 256 + threadIdx.x) * 2;
  int b = px0 >> 15, hw = px0 & 32767;
  bool isbf = ws[OFF_FLG] > 0.5f;
  int enc = (int)ws[OFF_FLG + 1];
  f32x2 s0 = {0.f, 0.f}, s1 = {0.f, 0.f}, s2 = {0.f, 0.f};
#pragma unroll
  for (int g = 0; g < 8; g++) {
    s0 += *(const f32x2*)(eap + (g * 3 + 0) * NPX + px0);
    s1 += *(const f32x2*)(eap + (g * 3 + 1) * NPX + px0);
    s2 += *(const f32x2*)(eap + (g * 3 + 2) * NPX + px0);
  }
  float m0 = mask_at(rawmask, b * HW + hw, enc);
  float m1 = mask_at(rawmask, b * HW + hw + 1, enc);
  float she0 = ws[OFF_SHE], she1 = ws[OFF_SHE + 1], she2 = ws[OFF_SHE + 2];
  float c0a, c0b, c1a, c1b, c2a, c2b;
  if (isbf) {
    const u16* cb = (const u16*)cart + b * 3 * HW;
    c0a = bf2f(cb[hw]); c0b = bf2f(cb[hw + 1]);
    c1a = bf2f(cb[HW + hw]); c1b = bf2f(cb[HW + hw + 1]);
    c2a = bf2f(cb[2 * HW + hw]); c2b = bf2f(cb[2 * HW + hw + 1]);
  } else {
    const float* cb = (const float*)cart + b * 3 * HW;
    c0a = cb[hw]; c0b = cb[hw + 1];
    c1a = cb[HW + hw]; c1b = cb[HW + hw + 1];
    c2a = cb[2 * HW + hw]; c2b = cb[2 * HW + hw + 1];
  }
  float r0a = c0a + (s0.x + she0) * m0, r0b = c0b + (s0.y + she0) * m1;
  float r1a = c1a + (s1.x + she1) * m0, r1b = c1b + (s1.y + she1) * m1;
  float r2a = c2a + (s2.x + she2) * m0, r2b = c2b + (s2.y + she2) * m1;
  int cbase = GEO_SIZE + b * 3 * HW + hw;
  if (isbf) {
    u16* o16 = (u16*)out;
    *(u32*)(o16 + cbase)          = (u32)f2bf(r0a) | ((u32)f2bf(r0b) << 16);
    *(u32*)(o16 + cbase + HW)     = (u32)f2bf(r1a) | ((u32)f2bf(r1b) << 16);
    *(u32*)(o16 + cbase + 2 * HW) = (u32)f2bf(r2a) | ((u32)f2bf(r2b) << 16);
  } else {
    float* of = (float*)out;
    of[cbase] = r0a; of[cbase + 1] = r0b;
    of[cbase + HW] = r1a; of[cbase + HW + 1] = r1b;
    of[cbase + 2 * HW] = r2a; of[cbase + 2 * HW + 1] = r2b;
  }
}

extern "C" void kernel_launch(void* const* d_in, const int* in_sizes, int n_in,
                              void* d_out, int out_size, void* d_ws, size_t ws_size,
                              hipStream_t stream) {
  const void* feat = d_in[0];
  const void* cart = d_in[1];
  const void* mask = d_in[2];
  float* ws  = (float*)d_ws;
  float* eap = (float*)((char*)d_ws + EAP_OFF);
  u16*  t    = (u16*)((char*)d_ws + T_OFF);

  hipLaunchKernelGGL(prep_kernel, dim3(33), dim3(256), 0, stream,
                     d_in[3], d_in[4], d_in[5], d_in[6], d_in[7],
                     d_in[8], d_in[9], d_in[10], d_in[11], d_in[12],
                     d_in[13], d_in[14], d_in[15], d_in[16], d_in[17],
                     mask, ws);
  hipLaunchKernelGGL(stage1_kernel, dim3(1024), dim3(256), 0, stream, feat, ws, t);
  hipLaunchKernelGGL(stage2_kernel, dim3(1024), dim3(256), 0, stream, cart, ws, mask, t, eap, d_out);
  hipLaunchKernelGGL(final_kernel, dim3(128), dim3(256), 0, stream, cart, ws, mask, eap, d_out);
}